// Round 1
// 442.109 us; speedup vs baseline: 1.2935x; 1.2935x over previous
//
#include <hip/hip_runtime.h>
#include <math.h>

#define N_ANGLES 180
#define P 724
#define W_IN 512

// ---------------- pre-kernels ----------------

// trig table: ws[0..179] = {cos, sin} per angle (float2)
__global__ __launch_bounds__(256) void prep_trig(float2* __restrict__ sc) {
    int a = threadIdx.x;
    if (a < N_ANGLES) {
        float deg = (float)a * (180.0f / 179.0f);
        float ang = deg * (float)(M_PI / 180.0);
        sc[a] = make_float2(cosf(ang), sinf(ang));
    }
}

// 512x512 transpose of the input into workspace (for |s|>|c| angles -> coalesced gathers)
__global__ __launch_bounds__(256) void prep_transpose(const float* __restrict__ in,
                                                      float* __restrict__ out) {
    __shared__ float tile[32][33];
    const int bx = blockIdx.x * 32, by = blockIdx.y * 32;
    const int tx = threadIdx.x, ty = threadIdx.y;   // block (32,8)
    #pragma unroll
    for (int r = 0; r < 32; r += 8)
        tile[ty + r][tx] = in[(by + ty + r) * W_IN + bx + tx];
    __syncthreads();
    #pragma unroll
    for (int r = 0; r < 32; r += 8)
        out[(bx + ty + r) * W_IN + by + tx] = tile[tx][ty + r];
}

// ---------------- main kernel ----------------
// MODE 2: trig from ws + transposed image available
// MODE 1: trig from ws, no transpose
// MODE 0: no workspace at all (inline trig)
template <int MODE>
__global__ __launch_bounds__(256) void radon_kernel(
    const float* __restrict__ x,       // [512,512]
    const float2* __restrict__ sc,     // [180] {c,s}
    const float* __restrict__ xT,      // [512,512] transposed (MODE==2)
    float* __restrict__ sino,          // [180,724]
    float* __restrict__ rot)           // [180,724,724]
{
    const int block = blockIdx.x;          // 0 .. 180*724-1  (SALU div by const)
    const int a = block / P;               // angle index
    const int i = block - a * P;           // output row
    const int tid = threadIdx.x;

    float c, s;
    if (MODE > 0) {
        float2 cs = sc[a];
        c = cs.x; s = cs.y;
    } else {
        float deg = (float)a * (180.0f / 179.0f);
        float ang = deg * (float)(M_PI / 180.0);
        c = cosf(ang); s = sinf(ang);
    }

    // coordinates collapse to ix = c*j + Kx, iy = s*j + Ky (unpadded coords, PAD folded in):
    //   ix = c*(j-361.5) - s*(i-361.5) + 361.5 - 106
    //   iy = s*(j-361.5) + c*(i-361.5) + 361.5 - 106
    const float fi = (float)i - 361.5f;
    const float Kx = 255.5f - 361.5f * c - s * fi;
    const float Ky = 255.5f - 361.5f * s + c * fi;

    // axis-swap: when |s|>|c| consecutive lanes move fastest in y -> read transposed copy
    const bool useT = (MODE == 2) && (fabsf(s) > fabsf(c));
    const float* __restrict__ bimg = useT ? xT : x;

    float* rrow = rot + (size_t)block * P;
    float lsum = 0.0f;

    #pragma unroll
    for (int k = 0; k < 3; ++k) {
        const int j = tid + (k << 8);
        if (j < P) {
            const float jf = (float)j;
            const float ix = fmaf(jf, c, Kx);
            const float iy = fmaf(jf, s, Ky);
            const float x0f = floorf(ix);
            const float y0f = floorf(iy);
            const int x0 = (int)x0f;
            const int y0 = (int)y0f;
            const int x1 = x0 + 1;
            const int y1 = y0 + 1;

            float val = 0.0f;
            // all 4 taps outside [0,512) => exact 0 (ref: pad zeros + oob mask)
            const bool outp = ((unsigned)x1 > 512u) || ((unsigned)y1 > 512u);
            if (!__all((int)outp)) {
                float wx1 = ix - x0f, wy1 = iy - y0f;
                float wx0 = 1.0f - wx1, wy0 = 1.0f - wy1;

                const bool inp = ((unsigned)x0 < 511u) && ((unsigned)y0 < 511u);
                if (__all((int)inp)) {
                    // fully interior wave: one base address, imm-offset taps
                    const int rr = useT ? x0 : y0;
                    const int cc = useT ? y0 : x0;
                    const float* bp = bimg + (rr << 9) + cc;
                    const float v00 = bp[0];
                    const float vA  = bp[1];      // fast-axis +1
                    const float vB  = bp[512];    // slow-axis +1
                    const float v11 = bp[513];
                    const float u0 = useT ? wy0 : wx0;
                    const float u1 = useT ? wy1 : wx1;
                    const float q0 = useT ? wx0 : wy0;
                    const float q1 = useT ? wx1 : wy1;
                    val = fmaf(q1, fmaf(u1, v11, u0 * vB),
                               q0 * fmaf(u1, vA, u0 * v00));
                } else {
                    // boundary wave: fold oob masks into weights, clamp (med3) indices
                    wx0 = ((unsigned)x0 < 512u) ? wx0 : 0.0f;
                    wx1 = ((unsigned)x1 < 512u) ? wx1 : 0.0f;
                    wy0 = ((unsigned)y0 < 512u) ? wy0 : 0.0f;
                    wy1 = ((unsigned)y1 < 512u) ? wy1 : 0.0f;
                    const int xc0 = min(max(x0, 0), 511);
                    const int xc1 = min(max(x1, 0), 511);
                    const int yc0 = min(max(y0, 0), 511);
                    const int yc1 = min(max(y1, 0), 511);
                    const int r0 = useT ? xc0 : yc0;
                    const int r1 = useT ? xc1 : yc1;
                    const int c0 = useT ? yc0 : xc0;
                    const int c1 = useT ? yc1 : xc1;
                    const float v00 = bimg[(r0 << 9) + c0];
                    const float vA  = bimg[(r0 << 9) + c1];
                    const float vB  = bimg[(r1 << 9) + c0];
                    const float v11 = bimg[(r1 << 9) + c1];
                    const float u0 = useT ? wy0 : wx0;
                    const float u1 = useT ? wy1 : wx1;
                    const float q0 = useT ? wx0 : wy0;
                    const float q1 = useT ? wx1 : wy1;
                    val = fmaf(q1, fmaf(u1, v11, u0 * vB),
                               q0 * fmaf(u1, vA, u0 * v00));
                }
            }
            __builtin_nontemporal_store(val, &rrow[j]);
            lsum += val;
        }
    }

    // block reduction: wave64 shuffle, then cross-wave via LDS
    for (int off = 32; off > 0; off >>= 1)
        lsum += __shfl_down(lsum, off, 64);

    __shared__ float ws_red[4];
    const int lane = tid & 63;
    const int wid  = tid >> 6;
    if (lane == 0) ws_red[wid] = lsum;
    __syncthreads();
    if (tid == 0)
        sino[block] = ws_red[0] + ws_red[1] + ws_red[2] + ws_red[3];
}

// ---------------- launch ----------------

extern "C" void kernel_launch(void* const* d_in, const int* in_sizes, int n_in,
                              void* d_out, int out_size, void* d_ws, size_t ws_size,
                              hipStream_t stream) {
    const float* x = (const float*)d_in[0];
    float* sino = (float*)d_out;                       // [180*724]
    float* rot  = sino + (size_t)N_ANGLES * P;         // [180*724*724]
    float* ws   = (float*)d_ws;

    const dim3 grid(N_ANGLES * P), blk(256);
    if (ws && ws_size >= (size_t)(512 + 512 * 512) * sizeof(float)) {
        float* xT = ws + 512;                          // trig table occupies first 512 floats
        prep_trig<<<dim3(1), dim3(256), 0, stream>>>((float2*)ws);
        prep_transpose<<<dim3(16, 16), dim3(32, 8), 0, stream>>>(x, xT);
        radon_kernel<2><<<grid, blk, 0, stream>>>(x, (const float2*)ws, xT, sino, rot);
    } else if (ws && ws_size >= (size_t)512 * sizeof(float)) {
        prep_trig<<<dim3(1), dim3(256), 0, stream>>>((float2*)ws);
        radon_kernel<1><<<grid, blk, 0, stream>>>(x, (const float2*)ws, nullptr, sino, rot);
    } else {
        radon_kernel<0><<<grid, blk, 0, stream>>>(x, nullptr, nullptr, sino, rot);
    }
}